// Round 14
// baseline (739.352 us; speedup 1.0000x reference)
//
#include <hip/hip_runtime.h>
#include <math.h>

#define Tn 1024
#define Bn 16
#define Sn 512
#define Vn 32
#define Cn 512
#define En 512
#define Ln 4
#define Kw 3
#define MROWS 16384
#define PADROWS 32
#define PADE (PADROWS * Cn)

typedef short bf16x8 __attribute__((ext_vector_type(8)));
typedef float f32x4 __attribute__((ext_vector_type(4)));

__device__ __forceinline__ unsigned short cvt_bf16(float x) {
  unsigned u = __builtin_bit_cast(unsigned, x);
  u = (u + 0x7FFFu + ((u >> 16) & 1u)) >> 16;
  return (unsigned short)u;
}
__device__ __forceinline__ float bf2f(unsigned short h) {
  unsigned u = ((unsigned)h) << 16;
  return __builtin_bit_cast(float, u);
}

#define GL16(g, l)                                                                     \
  __builtin_amdgcn_global_load_lds((const __attribute__((address_space(1))) void*)(g), \
                                   (__attribute__((address_space(3))) void*)(l), 16, 0, 0)

template <int N>
__device__ __forceinline__ void wait_vm_bar() {
  asm volatile("s_waitcnt vmcnt(%0)\n\ts_barrier" ::"i"(N) : "memory");
}
__device__ __forceinline__ void tail_bar() {
  asm volatile("s_waitcnt lgkmcnt(0)\n\ts_barrier" ::: "memory");
}
#define VMB(N)                                               \
  do {                                                       \
    asm volatile("s_waitcnt vmcnt(%0)" ::"i"(N) : "memory"); \
    __builtin_amdgcn_s_barrier();                            \
  } while (0)

__device__ __forceinline__ const unsigned short* seg_sel(const unsigned short* s0,
                                                         const unsigned short* s1,
                                                         const unsigned short* s2, int q) {
  const unsigned short* r = s0;
  r = (q == 1) ? s1 : r;
  r = (q == 2) ? s2 : r;
  return r;
}

// ---------------- g2: unified 128x128 BK=64 pipelined MFMA GEMM ----------------
// EPI: 0 glu-pair (interleaved Wcat)   4 plain bf16   5 ctx (fused den: dden=Esum)
template <int EPI, int NKT>
__global__ __launch_bounds__(512, 4) void g2(
    const unsigned short* __restrict__ a0, const unsigned short* __restrict__ a1,
    const unsigned short* __restrict__ a2, int ald, size_t az,
    const unsigned short* __restrict__ b0, const unsigned short* __restrict__ b1,
    const unsigned short* __restrict__ b2, int bld, size_t bz,
    const float* __restrict__ bias, const float* __restrict__ dden,
    unsigned short* __restrict__ out, int old_, size_t oz) {
  __shared__ char SA[32768], SB[32768];
  __shared__ float den_s[128];
  const int tid = threadIdx.x;
  const int lane = tid & 63, wave = tid >> 6;
  const int r15 = lane & 15;
  const int sq = ((lane >> 4) ^ ((r15 >> 1) & 3)) << 4;
  const int waveM = (wave >> 2) << 6;
  const int waveN = (wave & 3) << 5;
  const int m0 = blockIdx.x * 128, n0 = blockIdx.y * 128;
  const int z = blockIdx.z;
  const unsigned short* A0 = a0 + (size_t)z * az;
  const unsigned short* A1 = a1 + (size_t)z * az;
  const unsigned short* A2 = a2 + (size_t)z * az;
  const unsigned short* B0 = b0 + (size_t)z * bz;
  const unsigned short* B1 = b1 + (size_t)z * bz;
  const unsigned short* B2 = b2 + (size_t)z * bz;
  const int strow = tid >> 2;
  const int stcol = ((tid & 3) ^ ((tid >> 3) & 3)) << 3;
  const int lofs = tid * 16;
  f32x4 acc[4][2] = {};

  if constexpr (EPI == 5) {
    // den prologue: den_s[r] = d_row(m0+r, b=z) . Esum[z]   (dden = Esum base)
    int tl = tid >> 2, qt = tid & 3;
    const unsigned short* dp = A0 + (size_t)(m0 + tl) * ald + qt * 128;
    const float* ep = dden + z * 512 + qt * 128;
    float s = 0.f;
#pragma unroll
    for (int c = 0; c < 128; c += 8) {
      bf16x8 v = *(const bf16x8*)(dp + c);
      float4 e0 = *(const float4*)(ep + c);
      float4 e1 = *(const float4*)(ep + c + 4);
      s += bf2f((unsigned short)v[0]) * e0.x + bf2f((unsigned short)v[1]) * e0.y +
           bf2f((unsigned short)v[2]) * e0.z + bf2f((unsigned short)v[3]) * e0.w +
           bf2f((unsigned short)v[4]) * e1.x + bf2f((unsigned short)v[5]) * e1.y +
           bf2f((unsigned short)v[6]) * e1.z + bf2f((unsigned short)v[7]) * e1.w;
    }
    s += __shfl_xor(s, 1, 64);
    s += __shfl_xor(s, 2, 64);
    if (qt == 0) den_s[tl] = s;
    __syncthreads();
  }

#define STAGE_T(KT, SL)                                                               \
  do {                                                                                \
    const unsigned short* ab_ = seg_sel(A0, A1, A2, (KT) >> 3) +                      \
                                (size_t)(m0 + strow) * ald + (((KT)&7) << 6) + stcol; \
    const unsigned short* bb_ = seg_sel(B0, B1, B2, (KT) >> 3) +                      \
                                (size_t)(n0 + strow) * bld + (((KT)&7) << 6) + stcol; \
    GL16(ab_, SA + (SL)*16384 + lofs);                                                \
    GL16(ab_ + 32, SA + (SL)*16384 + 8192 + lofs);                                    \
    GL16(bb_, SB + (SL)*16384 + lofs);                                                \
    GL16(bb_ + 32, SB + (SL)*16384 + 8192 + lofs);                                    \
  } while (0)

  STAGE_T(0, 0);
  for (int kt = 0; kt < NKT; ++kt) {
    const int sl = kt & 1;
    if (kt + 1 < NKT) {
      STAGE_T(kt + 1, sl ^ 1);
      wait_vm_bar<4>();
    } else {
      wait_vm_bar<0>();
    }
    const char* abase = SA + sl * 16384 + (waveM + r15) * 64 + sq;
    const char* bbase = SB + sl * 16384 + (waveN + r15) * 64 + sq;
    __builtin_amdgcn_s_setprio(1);
#pragma unroll
    for (int kp = 0; kp < 2; ++kp) {
      bf16x8 af[4], bfv[2];
#pragma unroll
      for (int i = 0; i < 4; ++i) af[i] = *(const bf16x8*)(abase + kp * 8192 + i * 1024);
#pragma unroll
      for (int j = 0; j < 2; ++j) bfv[j] = *(const bf16x8*)(bbase + kp * 8192 + j * 1024);
#pragma unroll
      for (int i = 0; i < 4; ++i)
#pragma unroll
        for (int j = 0; j < 2; ++j)
          acc[i][j] = __builtin_amdgcn_mfma_f32_16x16x32_bf16(af[i], bfv[j], acc[i][j], 0, 0, 0);
    }
    __builtin_amdgcn_s_setprio(0);
    tail_bar();
  }
#undef STAGE_T

  const int q4 = (lane >> 4) << 2;
#pragma unroll
  for (int i = 0; i < 4; ++i) {
    int row = m0 + waveM + i * 16 + q4;
    if constexpr (EPI == 0) {
      int xcol = ((n0 + waveN) >> 1) + r15;
      float bx = bias[n0 + waveN + r15];
      float bg = bias[n0 + waveN + 16 + r15];
#pragma unroll
      for (int rr = 0; rr < 4; ++rr) {
        float xv = acc[i][0][rr] + bx;
        float gv = acc[i][1][rr] + bg;
        float sg = 1.f / (1.f + __expf(-gv));
        out[(size_t)(row + rr) * 512 + xcol] = cvt_bf16(xv * sg);
      }
    } else if constexpr (EPI == 5) {
#pragma unroll
      for (int rr = 0; rr < 4; ++rr) {
        float inv = 1.f / den_s[waveM + i * 16 + q4 + rr];
#pragma unroll
        for (int j = 0; j < 2; ++j) {
          int col = n0 + waveN + j * 16 + r15;
          out[(size_t)z * oz + (size_t)(row + rr) * old_ + col] = cvt_bf16(acc[i][j][rr] * inv);
        }
      }
    } else {
#pragma unroll
      for (int j = 0; j < 2; ++j) {
        int col = n0 + waveN + j * 16 + r15;
#pragma unroll
        for (int rr = 0; rr < 4; ++rr) {
          size_t o = (size_t)z * oz + (size_t)(row + rr) * old_ + col;
          out[o] = cvt_bf16(acc[i][j][rr]);
        }
      }
    }
  }
}

// ====== g3t: 256x128, BK=64, 2-phase/kt, counted-vmcnt, triple-K-segment GEMM ======
// EPI 1: bias + bf16 out ; EPI 2: bias + addbf + bf16 out
template <int EPI>
__global__ __launch_bounds__(512, 2) void g3t(
    const unsigned short* __restrict__ a0, const unsigned short* __restrict__ a1,
    const unsigned short* __restrict__ a2, const unsigned short* __restrict__ b0,
    const unsigned short* __restrict__ b1, const unsigned short* __restrict__ b2,
    const float* __restrict__ bias, const unsigned short* __restrict__ addbf,
    unsigned short* __restrict__ out) {
  __shared__ char LA[2][32768];
  __shared__ char LB[2][16384];
  const int tid = threadIdx.x;
  const int lane = tid & 63;
  const int wm = (tid >> 6) >> 1;
  const int wn = (tid >> 6) & 1;
  const int r15 = lane & 15;
  const int l4 = lane >> 4;
  const int q4 = l4 << 2;
  const int m0 = blockIdx.x * 256, n0 = blockIdx.y * 128;
  const int srow = tid >> 3;
  const int scol = (((tid & 7) ^ (srow & 7)) << 3);
  const int sdst = tid << 4;
  f32x4 acc[4][4] = {};
  bf16x8 afr[4][2], b01[2][2], b23[2][2];

#define TGA(KT, BB)                                                                \
  do {                                                                             \
    const unsigned short* s_ = seg_sel(a0, a1, a2, (KT) >> 3) +                    \
                               (size_t)(m0 + srow) * 512 + (((KT)&7) << 6) + scol; \
    GL16(s_, LA[BB] + sdst);                                                       \
    GL16(s_ + (size_t)64 * 512, LA[BB] + 8192 + sdst);                             \
    GL16(s_ + (size_t)128 * 512, LA[BB] + 16384 + sdst);                           \
    GL16(s_ + (size_t)192 * 512, LA[BB] + 24576 + sdst);                           \
  } while (0)
#define TGB(KT, BB)                                                                \
  do {                                                                             \
    const unsigned short* s_ = seg_sel(b0, b1, b2, (KT) >> 3) +                    \
                               (size_t)(n0 + srow) * 512 + (((KT)&7) << 6) + scol; \
    GL16(s_, LB[BB] + sdst);                                                       \
    GL16(s_ + (size_t)64 * 512, LB[BB] + 8192 + sdst);                             \
  } while (0)
#define TRA(SL)                                                                            \
  do {                                                                                     \
    _Pragma("unroll") for (int f = 0; f < 4; ++f) _Pragma("unroll") for (int kp = 0;       \
                                                                         kp < 2; ++kp) {  \
      int ar = ((f >> 1) << 7) + (wm << 5) + ((f & 1) << 4) + r15;                         \
      afr[f][kp] =                                                                         \
          *(const bf16x8*)(LA[SL] + ar * 128 + ((((kp << 2) | l4) ^ (ar & 7)) << 4));      \
    }                                                                                      \
  } while (0)
#define TRB(SL, CH, DST)                                                                   \
  do {                                                                                     \
    _Pragma("unroll") for (int c = 0; c < 2; ++c) _Pragma("unroll") for (int kp = 0;       \
                                                                         kp < 2; ++kp) {  \
      int br = ((CH) << 6) + (wn << 5) + (c << 4) + r15;                                   \
      DST[c][kp] =                                                                         \
          *(const bf16x8*)(LB[SL] + br * 128 + ((((kp << 2) | l4) ^ (br & 7)) << 4));      \
    }                                                                                      \
  } while (0)
#define MMT(BF, C0)                                                                        \
  do {                                                                                     \
    __builtin_amdgcn_s_setprio(1);                                                         \
    _Pragma("unroll") for (int f = 0; f < 4; ++f) _Pragma("unroll") for (int c = 0; c < 2; \
                                                                         ++c)             \
        _Pragma("unroll") for (int kp = 0; kp < 2; ++kp) acc[f][(C0) + c] =                \
            __builtin_amdgcn_mfma_f32_16x16x32_bf16(afr[f][kp], BF[c][kp],                 \
                                                    acc[f][(C0) + c], 0, 0, 0);            \
    __builtin_amdgcn_s_setprio(0);                                                         \
  } while (0)
#define TGRP(KT, W1, W2, STG)              \
  do {                                     \
    const int sl_ = (KT)&1, sn_ = sl_ ^ 1; \
    if (STG) TGA((KT) + 1, sn_);           \
    VMB(W1);                               \
    TRA(sl_);                              \
    TRB(sl_, 0, b01);                      \
    MMT(b01, 0);                           \
    if (STG) TGB((KT) + 1, sn_);           \
    VMB(W2);                               \
    TRB(sl_, 1, b23);                      \
    MMT(b23, 2);                           \
  } while (0)

  TGA(0, 0);
  TGB(0, 0);
  for (int kt = 0; kt < 23; ++kt) TGRP(kt, 5, 6, 1);
  TGRP(23, 1, 0, 0);
#undef TGRP

#pragma unroll
  for (int f = 0; f < 4; ++f) {
    int grow = m0 + ((f >> 1) << 7) + (wm << 5) + ((f & 1) << 4) + q4;
#pragma unroll
    for (int c = 0; c < 4; ++c) {
      int gcol = n0 + ((c >> 1) << 6) + (wn << 5) + ((c & 1) << 4) + r15;
      float bb = bias[gcol];
#pragma unroll
      for (int rr = 0; rr < 4; ++rr) {
        size_t o = (size_t)(grow + rr) * 512 + gcol;
        float v = acc[f][c][rr] + bb;
        if constexpr (EPI == 2) v += bf2f(addbf[o]);
        out[o] = cvt_bf16(v);
      }
    }
  }
}

// ---------------- MFMA output projection ----------------
__global__ __launch_bounds__(256, 4) void k_outm(const unsigned short* __restrict__ hd,
                                                 const unsigned short* __restrict__ embd,
                                                 const unsigned short* __restrict__ wcat2,
                                                 const float* __restrict__ bcat2,
                                                 float* __restrict__ out) {
  __shared__ char SA[32768];
  __shared__ char SBo[8192];
  const int tid = threadIdx.x;
  const int lane = tid & 63, wave = tid >> 6;
  const int r15 = lane & 15;
  const int sq = ((lane >> 4) ^ ((r15 >> 1) & 3)) << 4;
  const int waveM = wave << 5;
  const int m0 = blockIdx.x * 128;
  f32x4 acc[2][2] = {};

#define OSTAGE(KT, SL)                                                                   \
  do {                                                                                   \
    const unsigned short* aseg = ((KT) < 8) ? hd : embd;                                 \
    int kc = ((KT)&7) << 6;                                                              \
    _Pragma("unroll") for (int q = 0; q < 2; ++q) {                                      \
      int unit = q * 256 + tid;                                                          \
      int row = unit >> 2, chunk = unit & 3;                                             \
      int swc = chunk ^ ((row >> 1) & 3);                                                \
      GL16(aseg + (size_t)(m0 + row) * 512 + kc + swc * 8, SA + (SL)*16384 + unit * 16); \
      GL16(aseg + (size_t)(m0 + row) * 512 + kc + 32 + swc * 8,                          \
           SA + (SL)*16384 + 8192 + unit * 16);                                          \
    }                                                                                    \
    {                                                                                    \
      int half = tid >> 7;                                                               \
      int u = tid & 127;                                                                 \
      int row = u >> 2, chunk = u & 3;                                                   \
      int swc = chunk ^ ((row >> 1) & 3);                                                \
      GL16(wcat2 + (size_t)row * 1024 + ((KT) << 6) + half * 32 + swc * 8,               \
           SBo + (SL)*4096 + half * 2048 + u * 16);                                      \
    }                                                                                    \
  } while (0)

  OSTAGE(0, 0);
  for (int kt = 0; kt < 16; ++kt) {
    const int sl = kt & 1;
    if (kt + 1 < 16) {
      OSTAGE(kt + 1, sl ^ 1);
      wait_vm_bar<5>();
    } else {
      wait_vm_bar<0>();
    }
    const char* abase = SA + sl * 16384 + (waveM + r15) * 64 + sq;
    const char* bbase = SBo + sl * 4096 + r15 * 64 + sq;
    __builtin_amdgcn_s_setprio(1);
#pragma unroll
    for (int kp = 0; kp < 2; ++kp) {
      bf16x8 af[2], bfv[2];
#pragma unroll
      for (int i = 0; i < 2; ++i) af[i] = *(const bf16x8*)(abase + kp * 8192 + i * 1024);
#pragma unroll
      for (int j = 0; j < 2; ++j) bfv[j] = *(const bf16x8*)(bbase + kp * 2048 + j * 1024);
#pragma unroll
      for (int i = 0; i < 2; ++i)
#pragma unroll
        for (int j = 0; j < 2; ++j)
          acc[i][j] = __builtin_amdgcn_mfma_f32_16x16x32_bf16(af[i], bfv[j], acc[i][j], 0, 0, 0);
    }
    __builtin_amdgcn_s_setprio(0);
    tail_bar();
  }
#undef OSTAGE

  const int q4 = (lane >> 4) << 2;
#pragma unroll
  for (int i = 0; i < 2; ++i) {
    int row = m0 + waveM + i * 16 + q4;
#pragma unroll
    for (int j = 0; j < 2; ++j) {
      int col = j * 16 + r15;
      float bb = bcat2[col];
#pragma unroll
      for (int rr = 0; rr < 4; ++rr) out[(size_t)(row + rr) * 32 + col] = acc[i][j][rr] + bb;
    }
  }
}

// ---------------- setup kernels (separate) ----------------

__global__ __launch_bounds__(256) void emb_kernel(const int* __restrict__ labels,
                                                  const float* __restrict__ labW,
                                                  const float* __restrict__ timeW,
                                                  unsigned short* __restrict__ embd) {
  int idx = blockIdx.x * 256 + threadIdx.x;
  int dd = idx & 511;
  int m = idx >> 9;
  int t = m >> 4;
  embd[idx] = cvt_bf16(labW[labels[m] * 512 + dd] + timeW[t * 512 + dd]);
}

__global__ void k_zeropad(unsigned short* a, unsigned short* b, unsigned short* c) {
  int i = blockIdx.x * 256 + threadIdx.x;
  a[i] = 0; b[i] = 0; c[i] = 0;
}

__global__ void k_wcat(const float* __restrict__ wx, const float* __restrict__ wg,
                       unsigned short* __restrict__ wcat) {
  int idx = blockIdx.x * 256 + threadIdx.x;
  int k = idx % 1536;
  int tmp = idx / 1536;
  int orow = tmp & 1023;
  int l = tmp >> 10;
  int tap = k >> 9, c = k & 511;
  int q = orow >> 5, r = orow & 31;
  int srow = q * 16 + (r & 15);
  const float* src = (r < 16) ? wx : wg;
  float v = src[(((size_t)l * 512 + srow) * 512 + c) * 3 + tap];
  wcat[idx] = cvt_bf16(v);
}

__global__ void k_biascat(const float* __restrict__ bx, const float* __restrict__ bg,
                          float* __restrict__ bcat) {
  int idx = blockIdx.x * 256 + threadIdx.x;
  int orow = idx & 1023, l = idx >> 10;
  int q = orow >> 5, r = orow & 31;
  bcat[idx] = (r < 16) ? bx[l * 512 + q * 16 + r] : bg[l * 512 + q * 16 + (r & 15)];
}

__global__ void k_wcat2(const float* __restrict__ opw, const float* __restrict__ orw,
                        const float* __restrict__ opb, const float* __restrict__ orb,
                        unsigned short* __restrict__ wcat2, float* __restrict__ bcat2) {
  int idx = blockIdx.x * 256 + threadIdx.x;
  int v = idx >> 10, k = idx & 1023;
  float val = (k < 512) ? opw[v * 512 + k] : orw[v * 512 + k - 512];
  wcat2[idx] = cvt_bf16(val);
  if (idx < 32) bcat2[idx] = opb[idx] + orb[idx];
}

__global__ void cast_kernel(const float* __restrict__ src, unsigned short* __restrict__ dst,
                            int n) {
  int i = blockIdx.x * 256 + threadIdx.x;
  if (i < n) dst[i] = cvt_bf16(src[i]);
}

__global__ __launch_bounds__(256) void k_tr512(const float* __restrict__ w,
                                               unsigned short* __restrict__ wt) {
  __shared__ unsigned short t[64][65];
  int r0 = blockIdx.x * 64, c0 = blockIdx.y * 64;
  size_t base = (size_t)blockIdx.z * 512 * 512;
  int c = threadIdx.x & 63, rr = threadIdx.x >> 6;
#pragma unroll
  for (int i = 0; i < 16; ++i) {
    int r = rr + i * 4;
    t[r][c] = cvt_bf16(w[base + (size_t)(r0 + r) * 512 + c0 + c]);
  }
  __syncthreads();
#pragma unroll
  for (int i = 0; i < 16; ++i) {
    int r = rr + i * 4;
    wt[base + (size_t)(c0 + r) * 512 + r0 + c] = t[c][r];
  }
}

__global__ void esum_kernel(const float* __restrict__ enc, float* __restrict__ Esum) {
  int p = blockIdx.x * 256 + threadIdx.x;
  float s = 0.f;
  for (int ss = 0; ss < Sn; ++ss) s += enc[(size_t)ss * Bn * En + p];
  Esum[p] = s;
}

__global__ __launch_bounds__(256) void k_encT(const float* __restrict__ enc,
                                              unsigned short* __restrict__ encT) {
  __shared__ unsigned short t[64][66];
  int s0 = blockIdx.x * 64, e0 = blockIdx.y * 64, b = blockIdx.z;
  int c = threadIdx.x & 63, r0 = threadIdx.x >> 6;
#pragma unroll
  for (int i = 0; i < 16; ++i) {
    int r = r0 + i * 4;
    t[r][c] = cvt_bf16(enc[((size_t)(s0 + r) * Bn + b) * En + e0 + c]);
  }
  __syncthreads();
#pragma unroll
  for (int i = 0; i < 16; ++i) {
    int r = r0 + i * 4;
    encT[((size_t)b * En + e0 + r) * Sn + s0 + c] = t[c][r];
  }
}

__global__ void k_biasprep(const float* __restrict__ i2e, const float* __restrict__ res_b,
                           const float* __restrict__ in2enc_b, const float* __restrict__ lab2enc_b,
                           const float* __restrict__ e2i_b, const float* __restrict__ inres_b,
                           float* __restrict__ bd, float* __restrict__ bh) {
  int idx = blockIdx.x * 256 + threadIdx.x;
  int l = idx >> 9;
  float v = 0.f;
  const float* row = i2e + (size_t)idx * 512;
  const float* rb = res_b + l * 512;
  for (int c = 0; c < 512; ++c) v += row[c] * rb[c];
  bd[idx] = v + in2enc_b[idx] + lab2enc_b[idx];
  bh[idx] = res_b[idx] + e2i_b[idx] + inres_b[idx];
}

// ---------------- host ----------------

extern "C" void kernel_launch(void* const* d_in, const int* in_sizes, int n_in,
                              void* d_out, int out_size, void* d_ws, size_t ws_size,
                              hipStream_t stream) {
  const int* labels = (const int*)d_in[0];
  const float* enc = (const float*)d_in[1];
  const float* labW = (const float*)d_in[2];
  const float* timeW = (const float*)d_in[3];
  const float* conv_glu_w = (const float*)d_in[4];
  const float* conv_glu_b = (const float*)d_in[5];
  const float* conv_id_w = (const float*)d_in[6];
  const float* conv_id_b = (const float*)d_in[7];
  const float* res_proj_w = (const float*)d_in[8];
  const float* res_proj_b = (const float*)d_in[9];
  const float* inres_w = (const float*)d_in[10];
  const float* inres_b = (const float*)d_in[11];
  const float* in2enc_w = (const float*)d_in[12];
  const float* in2enc_b = (const float*)d_in[13];
  const float* lab2enc_w = (const float*)d_in[14];
  const float* lab2enc_b = (const float*)d_in[15];
  const float* enc2in_w = (const float*)d_in[16];
  const float* enc2in_b = (const float*)d_in[17];
  const float* out_res_w = (const float*)d_in[18];
  const float* out_res_b = (const float*)d_in[19];
  const float* out_proj_w = (const float*)d_in[20];
  const float* out_proj_b = (const float*)d_in[21];
  float* out = (float*)d_out;

  char* cur = (char*)d_ws;
  auto alloc = [&](size_t bytes) {
    char* p = cur;
    cur += (bytes + 255) & ~(size_t)255;
    return p;
  };
  const size_t BIG = (size_t)MROWS * 512;
  const size_t WN = (size_t)Ln * Cn * Cn;
  const size_t ZL = (size_t)512 * 512;
  float* EsumB = (float*)alloc(Bn * En * 4);
  float* bd = (float*)alloc(Ln * 512 * 4);
  float* bh = (float*)alloc(Ln * 512 * 4);
  float* bcat = (float*)alloc(Ln * 1024 * 4);
  float* bcat2 = (float*)alloc(32 * 4);
  unsigned short* embp = (unsigned short*)alloc((PADE + BIG) * 2);
  unsigned short* h0p = (unsigned short*)alloc((PADE + BIG) * 2);
  unsigned short* h1p = (unsigned short*)alloc((PADE + BIG) * 2);
  unsigned short* glubf = (unsigned short*)alloc(BIG * 2);
  unsigned short* dbf = (unsigned short*)alloc(BIG * 2);
  unsigned short* ctxbf = (unsigned short*)alloc(BIG * 2);
  unsigned short* encT = (unsigned short*)alloc((size_t)Bn * En * Sn * 2);
  unsigned short* Mbf = (unsigned short*)alloc((size_t)Bn * En * En * 2);
  unsigned short* wres = (unsigned short*)alloc(WN * 2);
  unsigned short* resT = (unsigned short*)alloc(WN * 2);
  unsigned short* wfuse = (unsigned short*)alloc(WN * 2);
  unsigned short* wcat = (unsigned short*)alloc((size_t)Ln * 1024 * 1536 * 2);
  unsigned short* wcat2 = (unsigned short*)alloc((size_t)32 * 1024 * 2);
  unsigned short* w_i2e = (unsigned short*)alloc(WN * 2);
  unsigned short* w_l2e = (unsigned short*)alloc(WN * 2);
  unsigned short* w_inr = (unsigned short*)alloc(WN * 2);
  unsigned short* w_e2i = (unsigned short*)alloc(WN * 2);

  unsigned short* embd = embp + PADE;
  unsigned short* h0d = h0p + PADE;
  unsigned short* h1d = h1p + PADE;

  // setup
  emb_kernel<<<MROWS * 512 / 256, 256, 0, stream>>>(labels, labW, timeW, embd);
  k_zeropad<<<PADE / 256, 256, 0, stream>>>(embp, h0p, h1p);
  k_wcat<<<Ln * 1024 * 1536 / 256, 256, 0, stream>>>(conv_glu_w, conv_id_w, wcat);
  k_biascat<<<Ln * 1024 / 256, 256, 0, stream>>>(conv_glu_b, conv_id_b, bcat);
  k_wcat2<<<32 * 1024 / 256, 256, 0, stream>>>(out_proj_w, out_res_w, out_proj_b, out_res_b,
                                               wcat2, bcat2);
  cast_kernel<<<WN / 256, 256, 0, stream>>>(res_proj_w, wres, WN);
  cast_kernel<<<WN / 256, 256, 0, stream>>>(in2enc_w, w_i2e, WN);
  cast_kernel<<<WN / 256, 256, 0, stream>>>(lab2enc_w, w_l2e, WN);
  cast_kernel<<<WN / 256, 256, 0, stream>>>(inres_w, w_inr, WN);
  cast_kernel<<<WN / 256, 256, 0, stream>>>(enc2in_w, w_e2i, WN);
  k_tr512<<<dim3(8, 8, Ln), 256, 0, stream>>>(res_proj_w, resT);
  k_biasprep<<<Ln * 512 / 256, 256, 0, stream>>>(in2enc_w, res_proj_b, in2enc_b, lab2enc_b,
                                                 enc2in_b, inres_b, bd, bh);
  esum_kernel<<<Bn * En / 256, 256, 0, stream>>>(enc, EsumB);
  k_encT<<<dim3(Sn / 64, En / 64, Bn), 256, 0, stream>>>(enc, encT);
  g2<4, 8><<<dim3(4, 4, Bn), 512, 0, stream>>>(encT, encT, encT, Sn, ZL, encT, encT, encT, Sn,
                                               ZL, nullptr, nullptr, Mbf, 512, ZL);
  g2<4, 8><<<dim3(4, 4, Ln), 512, 0, stream>>>(w_i2e, w_i2e, w_i2e, 512, ZL, resT, resT, resT,
                                               512, ZL, nullptr, nullptr, wfuse, 512, ZL);

  const unsigned short* hdata = embd;
  unsigned short* hbufs[2] = {h0d, h1d};
  for (int l = 0; l < Ln; ++l) {
    const size_t wo = (size_t)l * Cn * Cn;
    const unsigned short* wc = wcat + (size_t)l * 1024 * 1536;
    // glu = (h*Wx+bx)*sigmoid(h*Wg+bg)
    g2<0, 24><<<dim3(128, 8), 512, 0, stream>>>(hdata - 2 * Bn * 512, hdata - Bn * 512, hdata,
                                                512, 0, wc, wc + 512, wc + 1024, 1536, 0,
                                                bcat + l * 1024, nullptr, glubf, 512, 0);
    // d = glu@i2e + h@W' + emb@l2e + bd
    g3t<1><<<dim3(64, 4), 512, 0, stream>>>(glubf, hdata, embd, w_i2e + wo, wfuse + wo,
                                            w_l2e + wo, bd + l * 512, nullptr, dbf);
    // ctx = (d @ M[b]) / den  — den fused into prologue (dden = Esum)
    g2<5, 8><<<dim3(8, 4, Bn), 512, 0, stream>>>(dbf, dbf, dbf, 8192, 512, Mbf, Mbf, Mbf, 512,
                                                 ZL, nullptr, EsumB, ctxbf, 8192, 512);
    // h_out = h@res^T + ctx@e2i + emb@inres + bh + glu
    g3t<2><<<dim3(64, 4), 512, 0, stream>>>(hdata, ctxbf, embd, wres + wo, w_e2i + wo,
                                            w_inr + wo, bh + l * 512, glubf, hbufs[l & 1]);
    hdata = hbufs[l & 1];
  }

  k_outm<<<MROWS / 128, 256, 0, stream>>>(hdata, embd, wcat2, bcat2, out);
}

// Round 15
// 672.213 us; speedup vs baseline: 1.0999x; 1.0999x over previous
//
#include <hip/hip_runtime.h>
#include <math.h>

#define Tn 1024
#define Bn 16
#define Sn 512
#define Vn 32
#define Cn 512
#define En 512
#define Ln 4
#define Kw 3
#define MROWS 16384
#define PADROWS 32
#define PADE (PADROWS * Cn)

typedef short bf16x8 __attribute__((ext_vector_type(8)));
typedef float f32x4 __attribute__((ext_vector_type(4)));

__device__ __forceinline__ unsigned short cvt_bf16(float x) {
  unsigned u = __builtin_bit_cast(unsigned, x);
  u = (u + 0x7FFFu + ((u >> 16) & 1u)) >> 16;
  return (unsigned short)u;
}
__device__ __forceinline__ float bf2f(unsigned short h) {
  unsigned u = ((unsigned)h) << 16;
  return __builtin_bit_cast(float, u);
}

#define GL16(g, l)                                                                     \
  __builtin_amdgcn_global_load_lds((const __attribute__((address_space(1))) void*)(g), \
                                   (__attribute__((address_space(3))) void*)(l), 16, 0, 0)

template <int N>
__device__ __forceinline__ void wait_vm_bar() {
  asm volatile("s_waitcnt vmcnt(%0)\n\ts_barrier" ::"i"(N) : "memory");
}
__device__ __forceinline__ void tail_bar() {
  asm volatile("s_waitcnt lgkmcnt(0)\n\ts_barrier" ::: "memory");
}
#define VMB(N)                                               \
  do {                                                       \
    asm volatile("s_waitcnt vmcnt(%0)" ::"i"(N) : "memory"); \
    __builtin_amdgcn_s_barrier();                            \
  } while (0)

__device__ __forceinline__ const unsigned short* seg_sel(const unsigned short* s0,
                                                         const unsigned short* s1,
                                                         const unsigned short* s2, int q) {
  const unsigned short* r = s0;
  r = (q == 1) ? s1 : r;
  r = (q == 2) ? s2 : r;
  return r;
}

// ---------------- g2: unified 128x128 BK=64 pipelined MFMA GEMM ----------------
// EPI: 0 glu-pair (interleaved Wcat)   3 ctx (div den)   4 plain bf16
template <int EPI, int NKT>
__global__ __launch_bounds__(512, 4) void g2(
    const unsigned short* __restrict__ a0, const unsigned short* __restrict__ a1,
    const unsigned short* __restrict__ a2, int ald, size_t az,
    const unsigned short* __restrict__ b0, const unsigned short* __restrict__ b1,
    const unsigned short* __restrict__ b2, int bld, size_t bz,
    const float* __restrict__ bias, const float* __restrict__ dden,
    unsigned short* __restrict__ out, int old_, size_t oz) {
  __shared__ char SA[32768], SB[32768];
  const int tid = threadIdx.x;
  const int lane = tid & 63, wave = tid >> 6;
  const int r15 = lane & 15;
  const int sq = ((lane >> 4) ^ ((r15 >> 1) & 3)) << 4;
  const int waveM = (wave >> 2) << 6;
  const int waveN = (wave & 3) << 5;
  const int m0 = blockIdx.x * 128, n0 = blockIdx.y * 128;
  const int z = blockIdx.z;
  const unsigned short* A0 = a0 + (size_t)z * az;
  const unsigned short* A1 = a1 + (size_t)z * az;
  const unsigned short* A2 = a2 + (size_t)z * az;
  const unsigned short* B0 = b0 + (size_t)z * bz;
  const unsigned short* B1 = b1 + (size_t)z * bz;
  const unsigned short* B2 = b2 + (size_t)z * bz;
  const int strow = tid >> 2;
  const int stcol = ((tid & 3) ^ ((tid >> 3) & 3)) << 3;
  const int lofs = tid * 16;
  f32x4 acc[4][2] = {};

#define STAGE_T(KT, SL)                                                               \
  do {                                                                                \
    const unsigned short* ab_ = seg_sel(A0, A1, A2, (KT) >> 3) +                      \
                                (size_t)(m0 + strow) * ald + (((KT)&7) << 6) + stcol; \
    const unsigned short* bb_ = seg_sel(B0, B1, B2, (KT) >> 3) +                      \
                                (size_t)(n0 + strow) * bld + (((KT)&7) << 6) + stcol; \
    GL16(ab_, SA + (SL)*16384 + lofs);                                                \
    GL16(ab_ + 32, SA + (SL)*16384 + 8192 + lofs);                                    \
    GL16(bb_, SB + (SL)*16384 + lofs);                                                \
    GL16(bb_ + 32, SB + (SL)*16384 + 8192 + lofs);                                    \
  } while (0)

  STAGE_T(0, 0);
  for (int kt = 0; kt < NKT; ++kt) {
    const int sl = kt & 1;
    if (kt + 1 < NKT) {
      STAGE_T(kt + 1, sl ^ 1);
      wait_vm_bar<4>();
    } else {
      wait_vm_bar<0>();
    }
    const char* abase = SA + sl * 16384 + (waveM + r15) * 64 + sq;
    const char* bbase = SB + sl * 16384 + (waveN + r15) * 64 + sq;
    __builtin_amdgcn_s_setprio(1);
#pragma unroll
    for (int kp = 0; kp < 2; ++kp) {
      bf16x8 af[4], bfv[2];
#pragma unroll
      for (int i = 0; i < 4; ++i) af[i] = *(const bf16x8*)(abase + kp * 8192 + i * 1024);
#pragma unroll
      for (int j = 0; j < 2; ++j) bfv[j] = *(const bf16x8*)(bbase + kp * 8192 + j * 1024);
#pragma unroll
      for (int i = 0; i < 4; ++i)
#pragma unroll
        for (int j = 0; j < 2; ++j)
          acc[i][j] = __builtin_amdgcn_mfma_f32_16x16x32_bf16(af[i], bfv[j], acc[i][j], 0, 0, 0);
    }
    __builtin_amdgcn_s_setprio(0);
    tail_bar();
  }
#undef STAGE_T

  const int q4 = (lane >> 4) << 2;
#pragma unroll
  for (int i = 0; i < 4; ++i) {
    int row = m0 + waveM + i * 16 + q4;
    if constexpr (EPI == 0) {
      int xcol = ((n0 + waveN) >> 1) + r15;
      float bx = bias[n0 + waveN + r15];
      float bg = bias[n0 + waveN + 16 + r15];
#pragma unroll
      for (int rr = 0; rr < 4; ++rr) {
        float xv = acc[i][0][rr] + bx;
        float gv = acc[i][1][rr] + bg;
        float sg = 1.f / (1.f + __expf(-gv));
        out[(size_t)(row + rr) * 512 + xcol] = cvt_bf16(xv * sg);
      }
    } else if constexpr (EPI == 3) {
#pragma unroll
      for (int rr = 0; rr < 4; ++rr) {
        float inv = 1.f / dden[z + (size_t)(row + rr) * 16];
#pragma unroll
        for (int j = 0; j < 2; ++j) {
          int col = n0 + waveN + j * 16 + r15;
          out[(size_t)z * oz + (size_t)(row + rr) * old_ + col] = cvt_bf16(acc[i][j][rr] * inv);
        }
      }
    } else {
#pragma unroll
      for (int j = 0; j < 2; ++j) {
        int col = n0 + waveN + j * 16 + r15;
#pragma unroll
        for (int rr = 0; rr < 4; ++rr) {
          size_t o = (size_t)z * oz + (size_t)(row + rr) * old_ + col;
          out[o] = cvt_bf16(acc[i][j][rr]);
        }
      }
    }
  }
}

// ================= g3t: 256x128, BK=64, 2-phase/kt, triple-K-segment GEMM =================
// EPI 1: bias + bf16 out ; EPI 2: bias + addbf + bf16 out
template <int EPI>
__global__ __launch_bounds__(512, 2) void g3t(
    const unsigned short* __restrict__ a0, const unsigned short* __restrict__ a1,
    const unsigned short* __restrict__ a2, const unsigned short* __restrict__ b0,
    const unsigned short* __restrict__ b1, const unsigned short* __restrict__ b2,
    const float* __restrict__ bias, const unsigned short* __restrict__ addbf,
    unsigned short* __restrict__ out) {
  __shared__ char LA[2][32768];
  __shared__ char LB[2][16384];
  const int tid = threadIdx.x;
  const int lane = tid & 63;
  const int wm = (tid >> 6) >> 1;
  const int wn = (tid >> 6) & 1;
  const int r15 = lane & 15;
  const int l4 = lane >> 4;
  const int q4 = l4 << 2;
  const int m0 = blockIdx.x * 256, n0 = blockIdx.y * 128;
  const int srow = tid >> 3;
  const int scol = (((tid & 7) ^ (srow & 7)) << 3);
  const int sdst = tid << 4;
  f32x4 acc[4][4] = {};
  bf16x8 afr[4][2], b01[2][2], b23[2][2];

#define TGA(KT, BB)                                                                \
  do {                                                                             \
    const unsigned short* s_ = seg_sel(a0, a1, a2, (KT) >> 3) +                    \
                               (size_t)(m0 + srow) * 512 + (((KT)&7) << 6) + scol; \
    GL16(s_, LA[BB] + sdst);                                                       \
    GL16(s_ + (size_t)64 * 512, LA[BB] + 8192 + sdst);                             \
    GL16(s_ + (size_t)128 * 512, LA[BB] + 16384 + sdst);                           \
    GL16(s_ + (size_t)192 * 512, LA[BB] + 24576 + sdst);                           \
  } while (0)
#define TGB(KT, BB)                                                                \
  do {                                                                             \
    const unsigned short* s_ = seg_sel(b0, b1, b2, (KT) >> 3) +                    \
                               (size_t)(n0 + srow) * 512 + (((KT)&7) << 6) + scol; \
    GL16(s_, LB[BB] + sdst);                                                       \
    GL16(s_ + (size_t)64 * 512, LB[BB] + 8192 + sdst);                             \
  } while (0)
#define TRA(SL)                                                                            \
  do {                                                                                     \
    _Pragma("unroll") for (int f = 0; f < 4; ++f) _Pragma("unroll") for (int kp = 0;       \
                                                                         kp < 2; ++kp) {  \
      int ar = ((f >> 1) << 7) + (wm << 5) + ((f & 1) << 4) + r15;                         \
      afr[f][kp] =                                                                         \
          *(const bf16x8*)(LA[SL] + ar * 128 + ((((kp << 2) | l4) ^ (ar & 7)) << 4));      \
    }                                                                                      \
  } while (0)
#define TRB(SL, CH, DST)                                                                   \
  do {                                                                                     \
    _Pragma("unroll") for (int c = 0; c < 2; ++c) _Pragma("unroll") for (int kp = 0;       \
                                                                         kp < 2; ++kp) {  \
      int br = ((CH) << 6) + (wn << 5) + (c << 4) + r15;                                   \
      DST[c][kp] =                                                                         \
          *(const bf16x8*)(LB[SL] + br * 128 + ((((kp << 2) | l4) ^ (br & 7)) << 4));      \
    }                                                                                      \
  } while (0)
#define MMT(BF, C0)                                                                        \
  do {                                                                                     \
    __builtin_amdgcn_s_setprio(1);                                                         \
    _Pragma("unroll") for (int f = 0; f < 4; ++f) _Pragma("unroll") for (int c = 0; c < 2; \
                                                                         ++c)             \
        _Pragma("unroll") for (int kp = 0; kp < 2; ++kp) acc[f][(C0) + c] =                \
            __builtin_amdgcn_mfma_f32_16x16x32_bf16(afr[f][kp], BF[c][kp],                 \
                                                    acc[f][(C0) + c], 0, 0, 0);            \
    __builtin_amdgcn_s_setprio(0);                                                         \
  } while (0)
#define TGRP(KT, W1, W2, STG)              \
  do {                                     \
    const int sl_ = (KT)&1, sn_ = sl_ ^ 1; \
    if (STG) TGA((KT) + 1, sn_);           \
    VMB(W1);                               \
    TRA(sl_);                              \
    TRB(sl_, 0, b01);                      \
    MMT(b01, 0);                           \
    if (STG) TGB((KT) + 1, sn_);           \
    VMB(W2);                               \
    TRB(sl_, 1, b23);                      \
    MMT(b23, 2);                           \
  } while (0)

  TGA(0, 0);
  TGB(0, 0);
  for (int kt = 0; kt < 23; ++kt) TGRP(kt, 5, 6, 1);
  TGRP(23, 1, 0, 0);
#undef TGRP

#pragma unroll
  for (int f = 0; f < 4; ++f) {
    int grow = m0 + ((f >> 1) << 7) + (wm << 5) + ((f & 1) << 4) + q4;
#pragma unroll
    for (int c = 0; c < 4; ++c) {
      int gcol = n0 + ((c >> 1) << 6) + (wn << 5) + ((c & 1) << 4) + r15;
      float bb = bias[gcol];
#pragma unroll
      for (int rr = 0; rr < 4; ++rr) {
        size_t o = (size_t)(grow + rr) * 512 + gcol;
        float v = acc[f][c][rr] + bb;
        if constexpr (EPI == 2) v += bf2f(addbf[o]);
        out[o] = cvt_bf16(v);
      }
    }
  }
}

// den[row] = d[row] . Esum[b]
__global__ __launch_bounds__(256) void den_kernel(const unsigned short* __restrict__ d,
                                                  const float* __restrict__ Esum,
                                                  float* __restrict__ den) {
  int gtid = blockIdx.x * 256 + threadIdx.x;
  int row = gtid >> 6;
  int lane = threadIdx.x & 63;
  int b = row & 15;
  bf16x8 v = *(const bf16x8*)(d + (size_t)row * 512 + lane * 8);
  const float* ep = Esum + b * 512 + lane * 8;
  float4 e0 = *(const float4*)(ep);
  float4 e1 = *(const float4*)(ep + 4);
  float s = bf2f((unsigned short)v[0]) * e0.x + bf2f((unsigned short)v[1]) * e0.y +
            bf2f((unsigned short)v[2]) * e0.z + bf2f((unsigned short)v[3]) * e0.w +
            bf2f((unsigned short)v[4]) * e1.x + bf2f((unsigned short)v[5]) * e1.y +
            bf2f((unsigned short)v[6]) * e1.z + bf2f((unsigned short)v[7]) * e1.w;
  for (int off = 32; off; off >>= 1) s += __shfl_down(s, off, 64);
  if (lane == 0) den[row] = s;
}

// ---------------- MFMA output projection ----------------
__global__ __launch_bounds__(256, 4) void k_outm(const unsigned short* __restrict__ hd,
                                                 const unsigned short* __restrict__ embd,
                                                 const unsigned short* __restrict__ wcat2,
                                                 const float* __restrict__ bcat2,
                                                 float* __restrict__ out) {
  __shared__ char SA[32768];
  __shared__ char SBo[8192];
  const int tid = threadIdx.x;
  const int lane = tid & 63, wave = tid >> 6;
  const int r15 = lane & 15;
  const int sq = ((lane >> 4) ^ ((r15 >> 1) & 3)) << 4;
  const int waveM = wave << 5;
  const int m0 = blockIdx.x * 128;
  f32x4 acc[2][2] = {};

#define OSTAGE(KT, SL)                                                                   \
  do {                                                                                   \
    const unsigned short* aseg = ((KT) < 8) ? hd : embd;                                 \
    int kc = ((KT)&7) << 6;                                                              \
    _Pragma("unroll") for (int q = 0; q < 2; ++q) {                                      \
      int unit = q * 256 + tid;                                                          \
      int row = unit >> 2, chunk = unit & 3;                                             \
      int swc = chunk ^ ((row >> 1) & 3);                                                \
      GL16(aseg + (size_t)(m0 + row) * 512 + kc + swc * 8, SA + (SL)*16384 + unit * 16); \
      GL16(aseg + (size_t)(m0 + row) * 512 + kc + 32 + swc * 8,                          \
           SA + (SL)*16384 + 8192 + unit * 16);                                          \
    }                                                                                    \
    {                                                                                    \
      int half = tid >> 7;                                                               \
      int u = tid & 127;                                                                 \
      int row = u >> 2, chunk = u & 3;                                                   \
      int swc = chunk ^ ((row >> 1) & 3);                                                \
      GL16(wcat2 + (size_t)row * 1024 + ((KT) << 6) + half * 32 + swc * 8,               \
           SBo + (SL)*4096 + half * 2048 + u * 16);                                      \
    }                                                                                    \
  } while (0)

  OSTAGE(0, 0);
  for (int kt = 0; kt < 16; ++kt) {
    const int sl = kt & 1;
    if (kt + 1 < 16) {
      OSTAGE(kt + 1, sl ^ 1);
      wait_vm_bar<5>();
    } else {
      wait_vm_bar<0>();
    }
    const char* abase = SA + sl * 16384 + (waveM + r15) * 64 + sq;
    const char* bbase = SBo + sl * 4096 + r15 * 64 + sq;
    __builtin_amdgcn_s_setprio(1);
#pragma unroll
    for (int kp = 0; kp < 2; ++kp) {
      bf16x8 af[2], bfv[2];
#pragma unroll
      for (int i = 0; i < 2; ++i) af[i] = *(const bf16x8*)(abase + kp * 8192 + i * 1024);
#pragma unroll
      for (int j = 0; j < 2; ++j) bfv[j] = *(const bf16x8*)(bbase + kp * 2048 + j * 1024);
#pragma unroll
      for (int i = 0; i < 2; ++i)
#pragma unroll
        for (int j = 0; j < 2; ++j)
          acc[i][j] = __builtin_amdgcn_mfma_f32_16x16x32_bf16(af[i], bfv[j], acc[i][j], 0, 0, 0);
    }
    __builtin_amdgcn_s_setprio(0);
    tail_bar();
  }
#undef OSTAGE

  const int q4 = (lane >> 4) << 2;
#pragma unroll
  for (int i = 0; i < 2; ++i) {
    int row = m0 + waveM + i * 16 + q4;
#pragma unroll
    for (int j = 0; j < 2; ++j) {
      int col = j * 16 + r15;
      float bb = bcat2[col];
#pragma unroll
      for (int rr = 0; rr < 4; ++rr) out[(size_t)(row + rr) * 32 + col] = acc[i][j][rr] + bb;
    }
  }
}

// ---------------- merged setup kernels ----------------

__global__ __launch_bounds__(256) void k_prep2(const int* __restrict__ labels,
                                               const float* __restrict__ labW,
                                               const float* __restrict__ timeW,
                                               unsigned short* __restrict__ embd,
                                               unsigned short* __restrict__ embp,
                                               unsigned short* __restrict__ h0p,
                                               unsigned short* __restrict__ h1p) {
  int idx = blockIdx.x * 256 + threadIdx.x;
  if (idx < MROWS * 512) {
    int dd = idx & 511;
    int m = idx >> 9;
    int t = m >> 4;
    embd[idx] = cvt_bf16(labW[labels[m] * 512 + dd] + timeW[t * 512 + dd]);
    return;
  }
  int i = idx - MROWS * 512;
  if (i < PADE) embp[i] = 0;
  else if (i < 2 * PADE) h0p[i - PADE] = 0;
  else h1p[i - 2 * PADE] = 0;
}

__global__ __launch_bounds__(256) void k_prep1(
    const float* __restrict__ res_proj_w, const float* __restrict__ in2enc_w,
    const float* __restrict__ lab2enc_w, const float* __restrict__ inres_w,
    const float* __restrict__ enc2in_w, const float* __restrict__ wx,
    const float* __restrict__ wg, const float* __restrict__ cbx, const float* __restrict__ cbg,
    const float* __restrict__ opw, const float* __restrict__ orw, const float* __restrict__ opb,
    const float* __restrict__ orb, unsigned short* __restrict__ wres,
    unsigned short* __restrict__ w_i2e, unsigned short* __restrict__ w_l2e,
    unsigned short* __restrict__ w_inr, unsigned short* __restrict__ w_e2i,
    unsigned short* __restrict__ wcat, float* __restrict__ bcat,
    unsigned short* __restrict__ wcat2, float* __restrict__ bcat2) {
  int idx = blockIdx.x * 256 + threadIdx.x;
  const int WNc = 1 << 20;
  if (idx < 5 * WNc) {
    int which = idx >> 20, i = idx & (WNc - 1);
    const float* s = (which == 0)   ? res_proj_w
                     : (which == 1) ? in2enc_w
                     : (which == 2) ? lab2enc_w
                     : (which == 3) ? inres_w
                                    : enc2in_w;
    unsigned short* d = (which == 0)   ? wres
                        : (which == 1) ? w_i2e
                        : (which == 2) ? w_l2e
                        : (which == 3) ? w_inr
                                       : w_e2i;
    d[i] = cvt_bf16(s[i]);
    return;
  }
  idx -= 5 * WNc;
  if (idx < Ln * 1024 * 1536) {
    int k = idx % 1536;
    int tmp = idx / 1536;
    int orow = tmp & 1023;
    int l = tmp >> 10;
    int tap = k >> 9, c = k & 511;
    int q = orow >> 5, r = orow & 31;
    int srow = q * 16 + (r & 15);
    const float* src = (r < 16) ? wx : wg;
    wcat[idx] = cvt_bf16(src[(((size_t)l * 512 + srow) * 512 + c) * 3 + tap]);
    return;
  }
  idx -= Ln * 1024 * 1536;
  if (idx < Ln * 1024) {
    int orow = idx & 1023, l = idx >> 10;
    int q = orow >> 5, r = orow & 31;
    bcat[idx] = (r < 16) ? cbx[l * 512 + q * 16 + r] : cbg[l * 512 + q * 16 + (r & 15)];
    return;
  }
  idx -= Ln * 1024;
  {
    int v = idx >> 10, k = idx & 1023;
    float val = (k < 512) ? opw[v * 512 + k] : orw[v * 512 + k - 512];
    wcat2[idx] = cvt_bf16(val);
    if (idx < 32) bcat2[idx] = opb[idx] + orb[idx];
  }
}

__global__ __launch_bounds__(256) void k_tr512(const float* __restrict__ w,
                                               unsigned short* __restrict__ wt) {
  __shared__ unsigned short t[64][65];
  int r0 = blockIdx.x * 64, c0 = blockIdx.y * 64;
  size_t base = (size_t)blockIdx.z * 512 * 512;
  int c = threadIdx.x & 63, rr = threadIdx.x >> 6;
#pragma unroll
  for (int i = 0; i < 16; ++i) {
    int r = rr + i * 4;
    t[r][c] = cvt_bf16(w[base + (size_t)(r0 + r) * 512 + c0 + c]);
  }
  __syncthreads();
#pragma unroll
  for (int i = 0; i < 16; ++i) {
    int r = rr + i * 4;
    wt[base + (size_t)(c0 + r) * 512 + r0 + c] = t[c][r];
  }
}

__global__ void esum_kernel(const float* __restrict__ enc, float* __restrict__ Esum) {
  int p = blockIdx.x * 256 + threadIdx.x;
  float s = 0.f;
  for (int ss = 0; ss < Sn; ++ss) s += enc[(size_t)ss * Bn * En + p];
  Esum[p] = s;
}

__global__ __launch_bounds__(256) void k_encT(const float* __restrict__ enc,
                                              unsigned short* __restrict__ encT) {
  __shared__ unsigned short t[64][66];
  int s0 = blockIdx.x * 64, e0 = blockIdx.y * 64, b = blockIdx.z;
  int c = threadIdx.x & 63, r0 = threadIdx.x >> 6;
#pragma unroll
  for (int i = 0; i < 16; ++i) {
    int r = r0 + i * 4;
    t[r][c] = cvt_bf16(enc[((size_t)(s0 + r) * Bn + b) * En + e0 + c]);
  }
  __syncthreads();
#pragma unroll
  for (int i = 0; i < 16; ++i) {
    int r = r0 + i * 4;
    encT[((size_t)b * En + e0 + r) * Sn + s0 + c] = t[c][r];
  }
}

__global__ void k_biasprep(const float* __restrict__ i2e, const float* __restrict__ res_b,
                           const float* __restrict__ in2enc_b, const float* __restrict__ lab2enc_b,
                           const float* __restrict__ e2i_b, const float* __restrict__ inres_b,
                           float* __restrict__ bd, float* __restrict__ bh) {
  int idx = blockIdx.x * 256 + threadIdx.x;
  int l = idx >> 9;
  float v = 0.f;
  const float* row = i2e + (size_t)idx * 512;
  const float* rb = res_b + l * 512;
  for (int c = 0; c < 512; ++c) v += row[c] * rb[c];
  bd[idx] = v + in2enc_b[idx] + lab2enc_b[idx];
  bh[idx] = res_b[idx] + e2i_b[idx] + inres_b[idx];
}

// ---------------- host ----------------

extern "C" void kernel_launch(void* const* d_in, const int* in_sizes, int n_in,
                              void* d_out, int out_size, void* d_ws, size_t ws_size,
                              hipStream_t stream) {
  const int* labels = (const int*)d_in[0];
  const float* enc = (const float*)d_in[1];
  const float* labW = (const float*)d_in[2];
  const float* timeW = (const float*)d_in[3];
  const float* conv_glu_w = (const float*)d_in[4];
  const float* conv_glu_b = (const float*)d_in[5];
  const float* conv_id_w = (const float*)d_in[6];
  const float* conv_id_b = (const float*)d_in[7];
  const float* res_proj_w = (const float*)d_in[8];
  const float* res_proj_b = (const float*)d_in[9];
  const float* inres_w = (const float*)d_in[10];
  const float* inres_b = (const float*)d_in[11];
  const float* in2enc_w = (const float*)d_in[12];
  const float* in2enc_b = (const float*)d_in[13];
  const float* lab2enc_w = (const float*)d_in[14];
  const float* lab2enc_b = (const float*)d_in[15];
  const float* enc2in_w = (const float*)d_in[16];
  const float* enc2in_b = (const float*)d_in[17];
  const float* out_res_w = (const float*)d_in[18];
  const float* out_res_b = (const float*)d_in[19];
  const float* out_proj_w = (const float*)d_in[20];
  const float* out_proj_b = (const float*)d_in[21];
  float* out = (float*)d_out;

  char* cur = (char*)d_ws;
  auto alloc = [&](size_t bytes) {
    char* p = cur;
    cur += (bytes + 255) & ~(size_t)255;
    return p;
  };
  const size_t BIG = (size_t)MROWS * 512;
  const size_t WN = (size_t)Ln * Cn * Cn;
  const size_t ZL = (size_t)512 * 512;
  float* den = (float*)alloc(MROWS * 4);
  float* EsumB = (float*)alloc(Bn * En * 4);
  float* bd = (float*)alloc(Ln * 512 * 4);
  float* bh = (float*)alloc(Ln * 512 * 4);
  float* bcat = (float*)alloc(Ln * 1024 * 4);
  float* bcat2 = (float*)alloc(32 * 4);
  unsigned short* embp = (unsigned short*)alloc((PADE + BIG) * 2);
  unsigned short* h0p = (unsigned short*)alloc((PADE + BIG) * 2);
  unsigned short* h1p = (unsigned short*)alloc((PADE + BIG) * 2);
  unsigned short* glubf = (unsigned short*)alloc(BIG * 2);
  unsigned short* dbf = (unsigned short*)alloc(BIG * 2);
  unsigned short* ctxbf = (unsigned short*)alloc(BIG * 2);
  unsigned short* encT = (unsigned short*)alloc((size_t)Bn * En * Sn * 2);
  unsigned short* Mbf = (unsigned short*)alloc((size_t)Bn * En * En * 2);
  unsigned short* wres = (unsigned short*)alloc(WN * 2);
  unsigned short* resT = (unsigned short*)alloc(WN * 2);
  unsigned short* wfuse = (unsigned short*)alloc(WN * 2);
  unsigned short* wcat = (unsigned short*)alloc((size_t)Ln * 1024 * 1536 * 2);
  unsigned short* wcat2 = (unsigned short*)alloc((size_t)32 * 1024 * 2);
  unsigned short* w_i2e = (unsigned short*)alloc(WN * 2);
  unsigned short* w_l2e = (unsigned short*)alloc(WN * 2);
  unsigned short* w_inr = (unsigned short*)alloc(WN * 2);
  unsigned short* w_e2i = (unsigned short*)alloc(WN * 2);

  unsigned short* embd = embp + PADE;
  unsigned short* h0d = h0p + PADE;
  unsigned short* h1d = h1p + PADE;

  // setup (merged)
  k_prep2<<<(MROWS * 512 + 3 * PADE) / 256, 256, 0, stream>>>(labels, labW, timeW, embd, embp,
                                                              h0p, h1p);
  {
    int total = 5 * (1 << 20) + Ln * 1024 * 1536 + Ln * 1024 + 32 * 1024;
    k_prep1<<<total / 256, 256, 0, stream>>>(res_proj_w, in2enc_w, lab2enc_w, inres_w, enc2in_w,
                                             conv_glu_w, conv_id_w, conv_glu_b, conv_id_b,
                                             out_proj_w, out_res_w, out_proj_b, out_res_b, wres,
                                             w_i2e, w_l2e, w_inr, w_e2i, wcat, bcat, wcat2,
                                             bcat2);
  }
  k_tr512<<<dim3(8, 8, Ln), 256, 0, stream>>>(res_proj_w, resT);
  esum_kernel<<<Bn * En / 256, 256, 0, stream>>>(enc, EsumB);
  k_biasprep<<<Ln * 512 / 256, 256, 0, stream>>>(in2enc_w, res_proj_b, in2enc_b, lab2enc_b,
                                                 enc2in_b, inres_b, bd, bh);
  k_encT<<<dim3(Sn / 64, En / 64, Bn), 256, 0, stream>>>(enc, encT);
  g2<4, 8><<<dim3(4, 4, Bn), 512, 0, stream>>>(encT, encT, encT, Sn, ZL, encT, encT, encT, Sn,
                                               ZL, nullptr, nullptr, Mbf, 512, ZL);
  g2<4, 8><<<dim3(4, 4, Ln), 512, 0, stream>>>(w_i2e, w_i2e, w_i2e, 512, ZL, resT, resT, resT,
                                               512, ZL, nullptr, nullptr, wfuse, 512, ZL);

  const unsigned short* hdata = embd;
  unsigned short* hbufs[2] = {h0d, h1d};
  for (int l = 0; l < Ln; ++l) {
    const size_t wo = (size_t)l * Cn * Cn;
    const unsigned short* wc = wcat + (size_t)l * 1024 * 1536;
    // glu = (h*Wx+bx)*sigmoid(h*Wg+bg)  (proven g2 structure)
    g2<0, 24><<<dim3(128, 8), 512, 0, stream>>>(hdata - 2 * Bn * 512, hdata - Bn * 512, hdata,
                                                512, 0, wc, wc + 512, wc + 1024, 1536, 0,
                                                bcat + l * 1024, nullptr, glubf, 512, 0);
    // d = glu@i2e + h@W' + emb@l2e + bd
    g3t<1><<<dim3(64, 4), 512, 0, stream>>>(glubf, hdata, embd, w_i2e + wo, wfuse + wo,
                                            w_l2e + wo, bd + l * 512, nullptr, dbf);
    den_kernel<<<MROWS / 4, 256, 0, stream>>>(dbf, EsumB, den);
    // ctx = (d @ M[b]) / den
    g2<3, 8><<<dim3(8, 4, Bn), 512, 0, stream>>>(dbf, dbf, dbf, 8192, 512, Mbf, Mbf, Mbf, 512,
                                                 ZL, nullptr, den, ctxbf, 8192, 512);
    // h_out = h@res^T + ctx@e2i + emb@inres + bh + glu
    g3t<2><<<dim3(64, 4), 512, 0, stream>>>(hdata, ctxbf, embd, wres + wo, w_e2i + wo,
                                            w_inr + wo, bh + l * 512, glubf, hbufs[l & 1]);
    hdata = hbufs[l & 1];
  }

  k_outm<<<MROWS / 128, 256, 0, stream>>>(hdata, embd, wcat2, bcat2, out);
}